// Round 2
// baseline (425.237 us; speedup 1.0000x reference)
//
#include <hip/hip_runtime.h>

// ALiBi causal MHA: B=4, S=2048, D=1024, H=16, hd=64.
// Pipeline: cvt(fp32->bf16) -> GEMM(QKV) -> transposeV -> flash-attn -> GEMM(out, fp32)

typedef __bf16 bf16;
typedef __bf16 bf16x8 __attribute__((ext_vector_type(8)));
typedef float  f32x4  __attribute__((ext_vector_type(4)));

#define NEGINF (-1e30f)

__device__ __forceinline__ void gll16(const void* g, void* l) {
  __builtin_amdgcn_global_load_lds(
      (const __attribute__((address_space(1))) void*)g,
      (__attribute__((address_space(3))) void*)l, 16, 0, 0);
}

// ---------------- fp32 -> bf16 convert, 8 elems/thread ----------------
__global__ __launch_bounds__(256) void cvt_bf16(const float* __restrict__ in,
                                                bf16* __restrict__ out, int n8) {
  int i = blockIdx.x * 256 + threadIdx.x;
  if (i >= n8) return;
  const float4* p = (const float4*)in;
  float4 a = p[2 * i], b = p[2 * i + 1];
  bf16x8 r;
  r[0] = (bf16)a.x; r[1] = (bf16)a.y; r[2] = (bf16)a.z; r[3] = (bf16)a.w;
  r[4] = (bf16)b.x; r[5] = (bf16)b.y; r[6] = (bf16)b.z; r[7] = (bf16)b.w;
  *(bf16x8*)(out + 8 * i) = r;
}

// ---------------- C = A * B^T (+bias). A[M][K], Bt[N][K] bf16 row-major ----------------
// 128x128 tile, BK=32, 256 threads (4 waves, 2x2), 16x16x32 bf16 MFMA. m97 structure.
template <int OUTF32>
__global__ __launch_bounds__(256) void gemm_bt(const bf16* __restrict__ A,
                                               const bf16* __restrict__ Bt,
                                               const float* __restrict__ bias,
                                               void* __restrict__ Cout,
                                               int M, int N, int K) {
  __shared__ bf16 As[128 * 32];
  __shared__ bf16 Bs[128 * 32];
  const int tid = threadIdx.x;
  const int w = tid >> 6, l = tid & 63;
  const int t = l & 15, g = l >> 4;
  const int wr = w >> 1, wc = w & 1;
  const int tiles_n = N >> 7;
  const int bm = blockIdx.x / tiles_n, bn = blockIdx.x % tiles_n;
  const bf16* Ab = A + (long)(bm * 128) * K;
  const bf16* Bb = Bt + (long)(bn * 128) * K;

  f32x4 acc[4][4] = {};

  const int srow = w * 16 + (l >> 2);   // staging row within 64-row half
  const int scol = (l & 3) * 8;         // staging col (elems)
  char* AsB = (char*)As;
  char* BsB = (char*)Bs;

  for (int kt = 0; kt < K; kt += 32) {
    __syncthreads();
    gll16(Ab + (long)(srow)*K + kt + scol,      AsB + w * 1024);
    gll16(Ab + (long)(srow + 64) * K + kt + scol, AsB + 4096 + w * 1024);
    gll16(Bb + (long)(srow)*K + kt + scol,      BsB + w * 1024);
    gll16(Bb + (long)(srow + 64) * K + kt + scol, BsB + 4096 + w * 1024);
    __syncthreads();

    bf16x8 af[4], bfr[4];
#pragma unroll
    for (int m = 0; m < 4; m++)
      af[m] = *(const bf16x8*)(AsB + (wr * 64 + m * 16 + t) * 64 + g * 16);
#pragma unroll
    for (int n = 0; n < 4; n++)
      bfr[n] = *(const bf16x8*)(BsB + (wc * 64 + n * 16 + t) * 64 + g * 16);
#pragma unroll
    for (int m = 0; m < 4; m++)
#pragma unroll
      for (int n = 0; n < 4; n++)
        acc[m][n] = __builtin_amdgcn_mfma_f32_16x16x32_bf16(af[m], bfr[n], acc[m][n], 0, 0, 0);
  }

  // epilogue: C row = 4g+r per reg, col = t (per 16x16 frag)
#pragma unroll
  for (int m = 0; m < 4; m++) {
#pragma unroll
    for (int n = 0; n < 4; n++) {
      const int col = bn * 128 + wc * 64 + n * 16 + t;
      const float bv = bias[wc * 64 + n * 16 + t + bn * 128];
#pragma unroll
      for (int r = 0; r < 4; r++) {
        const int row = bm * 128 + wr * 64 + m * 16 + 4 * g + r;
        const float v = acc[m][n][r] + bv;
        if (OUTF32)
          ((float*)Cout)[(long)row * N + col] = v;
        else
          ((bf16*)Cout)[(long)row * N + col] = (bf16)v;
      }
    }
  }
}

// ---------------- transpose V: qkv[:, 2048+h*64+d] -> vT[bh][d][s] ----------------
// 64 tokens x 64 dims per block; 256 threads handle 2 rows each on both sides.
__global__ __launch_bounds__(256) void transpose_v(const bf16* __restrict__ qkv,
                                                   bf16* __restrict__ vT) {
  __shared__ bf16 tile[64][72];
  const int bid = blockIdx.x;
  const int st = bid & 31, bh = bid >> 5;
  const int b = bh >> 4, h = bh & 15;
  const int tid = threadIdx.x;
  const int r = tid >> 3, c = tid & 7;  // r in [0,32)

#pragma unroll
  for (int i = 0; i < 2; i++) {
    const int row = r + i * 32;  // token within 64-block
    const bf16* src =
        qkv + ((long)(b * 2048 + st * 64 + row)) * 3072 + 2048 + h * 64 + c * 8;
    bf16x8 v = *(const bf16x8*)src;
#pragma unroll
    for (int j = 0; j < 8; j++) tile[row][c * 8 + j] = v[j];
  }
  __syncthreads();
#pragma unroll
  for (int i = 0; i < 2; i++) {
    const int d = r + i * 32;  // head dim
    bf16x8 o;
#pragma unroll
    for (int j = 0; j < 8; j++) o[j] = tile[c * 8 + j][d];
    *(bf16x8*)(vT + ((long)bh * 64 + d) * 2048 + st * 64 + c * 8) = o;
  }
}

// ---------------- flash attention w/ ALiBi causal ----------------
// grid: bh(64) * qtiles(32). 256 threads = 4 waves, wave w owns q rows q0+w*16..+16.
// KV blocks of 64. K staged [kv][d] swizzled, V staged from vT as [d][kv] swizzled.
__global__ __launch_bounds__(256) void attn_fwd(const bf16* __restrict__ qkv,
                                                const bf16* __restrict__ vT,
                                                bf16* __restrict__ outp) {
  __shared__ bf16 Ks[64 * 64];
  __shared__ bf16 Vs[64 * 64];
  __shared__ bf16 Ps[4][16 * 64];

  const int bid = blockIdx.x;
  const int qt = bid & 31, bh = bid >> 5;
  const int b = bh >> 4, h = bh & 15;
  const int tid = threadIdx.x;
  const int w = tid >> 6, l = tid & 63;
  const int t = l & 15, g = l >> 4;

  const int q0 = qt * 64;
  const long tokbase = (long)b * 2048;

  // Q fragments (A operand: lane row = t, k = g*8+j)
  const int qrow = q0 + w * 16 + t;
  const bf16* qptr = qkv + (tokbase + qrow) * 3072 + h * 64;
  const bf16x8 qf0 = *(const bf16x8*)(qptr + g * 8);
  const bf16x8 qf1 = *(const bf16x8*)(qptr + 32 + g * 8);

  f32x4 o[4];
  float mr[4], lr[4];
#pragma unroll
  for (int i = 0; i < 4; i++) {
    o[i] = (f32x4){0.f, 0.f, 0.f, 0.f};
    mr[i] = NEGINF;
    lr[i] = 0.f;
  }

  const bf16* Kg = qkv + tokbase * 3072 + 1024 + h * 64;
  const bf16* Vg = vT + (long)bh * 64 * 2048;
  const int r8 = l >> 3, c8 = l & 7;
  const int sc = c8 ^ r8;  // pre-swizzled source chunk (LDS dest stays linear)
  char* pb = (char*)Ps[w];

  const int kvend = q0 + 64;
  for (int kv0 = 0; kv0 < kvend; kv0 += 64) {
    __syncthreads();
#pragma unroll
    for (int i = 0; i < 2; i++) {
      gll16(Kg + (long)(kv0 + i * 32 + w * 8 + r8) * 3072 + sc * 8,
            (char*)Ks + i * 4096 + w * 1024);
      gll16(Vg + (long)(i * 32 + w * 8 + r8) * 2048 + kv0 + sc * 8,
            (char*)Vs + i * 4096 + w * 1024);
    }
    __syncthreads();

    // S = Q K^T /8 + alibi ; S[q=4g+r][kv=nt*16+t]
    float sv[4][4];
#pragma unroll
    for (int nt = 0; nt < 4; nt++) {
      const int row = nt * 16 + t;
      const bf16x8 k0 = *(const bf16x8*)((char*)Ks + row * 128 + ((g) ^ (t & 7)) * 16);
      const bf16x8 k1 = *(const bf16x8*)((char*)Ks + row * 128 + ((g + 4) ^ (t & 7)) * 16);
      f32x4 s = {0.f, 0.f, 0.f, 0.f};
      s = __builtin_amdgcn_mfma_f32_16x16x32_bf16(qf0, k0, s, 0, 0, 0);
      s = __builtin_amdgcn_mfma_f32_16x16x32_bf16(qf1, k1, s, 0, 0, 0);
      const int kg = kv0 + nt * 16 + t;
#pragma unroll
      for (int r = 0; r < 4; r++) {
        const int qg = q0 + w * 16 + 4 * g + r;
        const float bias = (kg <= qg) ? (float)(kg - qg) : NEGINF;
        sv[nt][r] = s[r] * 0.125f + bias;
      }
    }

    // online softmax per q row (reduce over t: xor 1,2,4,8 stays in 16-lane group)
#pragma unroll
    for (int r = 0; r < 4; r++) {
      float mx = fmaxf(fmaxf(sv[0][r], sv[1][r]), fmaxf(sv[2][r], sv[3][r]));
      mx = fmaxf(mx, __shfl_xor(mx, 1, 64));
      mx = fmaxf(mx, __shfl_xor(mx, 2, 64));
      mx = fmaxf(mx, __shfl_xor(mx, 4, 64));
      mx = fmaxf(mx, __shfl_xor(mx, 8, 64));
      const float mn = fmaxf(mr[r], mx);
      const float alpha = __expf(mr[r] - mn);
      mr[r] = mn;
      float rs = 0.f;
#pragma unroll
      for (int nt = 0; nt < 4; nt++) {
        const float p = __expf(sv[nt][r] - mn);
        sv[nt][r] = p;
        rs += p;
      }
      rs += __shfl_xor(rs, 1, 64);
      rs += __shfl_xor(rs, 2, 64);
      rs += __shfl_xor(rs, 4, 64);
      rs += __shfl_xor(rs, 8, 64);
      lr[r] = lr[r] * alpha + rs;
      o[0][r] *= alpha; o[1][r] *= alpha; o[2][r] *= alpha; o[3][r] *= alpha;
    }

    // P -> per-wave LDS (swizzled), then read back as A-operand (rows = t)
#pragma unroll
    for (int nt = 0; nt < 4; nt++) {
      const int cd = nt * 2 + (t >> 3);
#pragma unroll
      for (int r = 0; r < 4; r++) {
        const int row = 4 * g + r;
        *(bf16*)(pb + row * 128 + (cd ^ (row & 7)) * 16 + (t & 7) * 2) = (bf16)sv[nt][r];
      }
    }

    // O += P V   (A = P[16q][64kv], B = V[kv][d] read from Vs[d][kv])
#pragma unroll
    for (int sub = 0; sub < 2; sub++) {
      const bf16x8 pa = *(const bf16x8*)(pb + t * 128 + ((g + 4 * sub) ^ (t & 7)) * 16);
#pragma unroll
      for (int dt = 0; dt < 4; dt++) {
        const int vrow = dt * 16 + t;
        const bf16x8 vf =
            *(const bf16x8*)((char*)Vs + vrow * 128 + ((g + 4 * sub) ^ (t & 7)) * 16);
        o[dt] = __builtin_amdgcn_mfma_f32_16x16x32_bf16(pa, vf, o[dt], 0, 0, 0);
      }
    }
  }

  // epilogue: out[q][d] = o/l
#pragma unroll
  for (int dt = 0; dt < 4; dt++) {
#pragma unroll
    for (int r = 0; r < 4; r++) {
      const int qg = q0 + w * 16 + 4 * g + r;
      const float val = o[dt][r] / lr[r];
      outp[(tokbase + qg) * 1024 + h * 64 + dt * 16 + t] = (bf16)val;
    }
  }
}

extern "C" void kernel_launch(void* const* d_in, const int* in_sizes, int n_in,
                              void* d_out, int out_size, void* d_ws, size_t ws_size,
                              hipStream_t stream) {
  (void)in_sizes; (void)n_in; (void)out_size; (void)ws_size;
  const float* x     = (const float*)d_in[0];
  const float* w_qkv = (const float*)d_in[1];
  const float* b_qkv = (const float*)d_in[2];
  const float* w_out = (const float*)d_in[3];
  const float* b_out = (const float*)d_in[4];
  float* out = (float*)d_out;

  char* ws = (char*)d_ws;
  bf16* xb    = (bf16*)(ws);                 // 16.8 MB (reused as attn out)
  bf16* wqkvb = (bf16*)(ws + 16777216);      // 6.3 MB
  bf16* woutb = (bf16*)(ws + 23068672);      // 2.1 MB
  bf16* qkvb  = (bf16*)(ws + 25165824);      // 50.3 MB
  bf16* vTb   = (bf16*)(ws + 75497472);      // 16.8 MB  (total 92.3 MB)
  bf16* attb  = xb;                          // alias: x dead after QKV GEMM

  cvt_bf16<<<4096, 256, 0, stream>>>(x, xb, 8192 * 1024 / 8);
  cvt_bf16<<<1536, 256, 0, stream>>>(w_qkv, wqkvb, 3072 * 1024 / 8);
  cvt_bf16<<<512, 256, 0, stream>>>(w_out, woutb, 1024 * 1024 / 8);

  gemm_bt<0><<<64 * 24, 256, 0, stream>>>(xb, wqkvb, b_qkv, (void*)qkvb, 8192, 3072, 1024);
  transpose_v<<<2048, 256, 0, stream>>>(qkvb, vTb);
  attn_fwd<<<2048, 256, 0, stream>>>(qkvb, vTb, attb);
  gemm_bt<1><<<64 * 8, 256, 0, stream>>>(attb, woutb, b_out, (void*)out, 8192, 1024, 1024);
}